// Round 1
// baseline (187.591 us; speedup 1.0000x reference)
//
#include <hip/hip_runtime.h>

#define SEQ 2048
#define DIM 128
#define KVB 64

typedef __attribute__((ext_vector_type(8))) short bf16x8;
typedef __attribute__((ext_vector_type(4))) short short4v;
typedef __attribute__((ext_vector_type(4))) float f32x4;

__device__ __forceinline__ short f2bf(float f) {
  union { float f; unsigned u; } v; v.f = f;
  unsigned r = v.u + 0x7FFFu + ((v.u >> 16) & 1u);  // RNE
  return (short)(r >> 16);
}

// Trust-weighted attention: context = sum_k t_k*exp((q.k/sqrt(D))*t_k) * v_k / sum_k (same weights)
// One block = 64 Q rows (4 waves x 16). KV streamed in 64-row LDS tiles.
__global__ __launch_bounds__(256, 2)
void trust_attn_kernel(const float* __restrict__ Qg, const float* __restrict__ Kg,
                       const float* __restrict__ Vg, const float* __restrict__ Tg,
                       float* __restrict__ Og) {
  __shared__ short Klds[KVB * DIM];      // [64][128] bf16 rows, XOR-swizzled (^((row&7)<<4) on byte addr)
  __shared__ short Vlds[DIM * KVB];      // V^T: [128][64] bf16 rows, XOR-swizzled
  __shared__ short Plds[4][16 * KVB];    // per-wave P tile [16][64] bf16, XOR-swizzled
  __shared__ float Tlds[KVB];

  const int b = blockIdx.y;
  const int qbase = blockIdx.x * 64;
  const int tid = (int)threadIdx.x;
  const int w = tid >> 6;
  const int l = tid & 63;
  const int lr = l & 15;    // A-row / B-col / D-col index
  const int lg = l >> 4;    // k-group

  const float* Qb = Qg + (size_t)b * SEQ * DIM;
  const float* Kb = Kg + (size_t)b * SEQ * DIM;
  const float* Vb = Vg + (size_t)b * SEQ * DIM;
  const float* Tb = Tg + (size_t)b * SEQ;
  float*       Ob = Og + (size_t)b * SEQ * DIM;

  // Q fragments (A-operand, M=16 rows of this wave): row=lr, k-slot j -> d = kk*32 + lg*8 + j
  bf16x8 qf[4];
  {
    const float* qrow = Qb + (size_t)(qbase + w * 16 + lr) * DIM;
    #pragma unroll
    for (int kk = 0; kk < 4; ++kk) {
      const float4 a = *(const float4*)(qrow + kk * 32 + lg * 8);
      const float4 c = *(const float4*)(qrow + kk * 32 + lg * 8 + 4);
      bf16x8 f;
      f[0] = f2bf(a.x); f[1] = f2bf(a.y); f[2] = f2bf(a.z); f[3] = f2bf(a.w);
      f[4] = f2bf(c.x); f[5] = f2bf(c.y); f[6] = f2bf(c.z); f[7] = f2bf(c.w);
      qf[kk] = f;
    }
  }

  f32x4 acc[8];
  #pragma unroll
  for (int nt = 0; nt < 8; ++nt) acc[nt] = f32x4{0.f, 0.f, 0.f, 0.f};
  float lsum[4] = {0.f, 0.f, 0.f, 0.f};

  for (int kv0 = 0; kv0 < SEQ; kv0 += KVB) {
    __syncthreads();  // previous tile's LDS reads done before overwrite

    // ---- stage K tile [64][128] fp32 -> bf16, swizzled ----
    #pragma unroll
    for (int i = 0; i < 8; ++i) {
      int flat4 = i * 256 + tid;          // float4-granular index, 0..2047
      int r = flat4 >> 5;                 // key row 0..63
      int c4 = (flat4 & 31) << 2;         // d col, multiple of 4
      const float4 f = *(const float4*)(Kb + (size_t)(kv0 + r) * DIM + c4);
      short4v pk;
      pk[0] = f2bf(f.x); pk[1] = f2bf(f.y); pk[2] = f2bf(f.z); pk[3] = f2bf(f.w);
      int byte_off = (r * 256 + (c4 << 1)) ^ ((r & 7) << 4);
      *(short4v*)((char*)Klds + byte_off) = pk;
    }
    // ---- stage V^T tile [128][64] fp32 -> bf16, transposed scatter, swizzled ----
    #pragma unroll
    for (int i = 0; i < 8; ++i) {
      int flat4 = i * 256 + tid;
      int r = flat4 >> 5;                 // key row 0..63
      int c4 = (flat4 & 31) << 2;         // d col
      const float4 f = *(const float4*)(Vb + (size_t)(kv0 + r) * DIM + c4);
      float vals[4] = {f.x, f.y, f.z, f.w};
      #pragma unroll
      for (int e = 0; e < 4; ++e) {
        int d = c4 + e;
        int byte_off = (d * 128 + (r << 1)) ^ ((d & 7) << 4);
        *(short*)((char*)Vlds + byte_off) = f2bf(vals[e]);
      }
    }
    if (tid < KVB) Tlds[tid] = Tb[kv0 + tid];
    __syncthreads();

    // ---- QK^T: S[q=4*lg+r][key=16*kt+lr] (D-layout per m89) ----
    f32x4 s[4];
    #pragma unroll
    for (int kt = 0; kt < 4; ++kt) {
      f32x4 a0 = f32x4{0.f, 0.f, 0.f, 0.f};
      #pragma unroll
      for (int kk = 0; kk < 4; ++kk) {
        int row = kt * 16 + lr;
        int byte_off = (row * 256 + ((kk * 32 + lg * 8) << 1)) ^ ((row & 7) << 4);
        bf16x8 kf = *(const bf16x8*)((char*)Klds + byte_off);
        a0 = __builtin_amdgcn_mfma_f32_16x16x32_bf16(qf[kk], kf, a0, 0, 0, 0);
      }
      s[kt] = a0;
    }

    // ---- weights: p = t * exp2(score * t * log2(e)/sqrt(D)); no max needed (|score|<~12) ----
    short* Pw = Plds[w];
    #pragma unroll
    for (int kt = 0; kt < 4; ++kt) {
      float t = Tlds[kt * 16 + lr];
      float tc = t * 0.12751743f;  // log2(e)/sqrt(128)
      #pragma unroll
      for (int r = 0; r < 4; ++r) {
        float p = t * exp2f(s[kt][r] * tc);
        lsum[r] += p;
        int q = lg * 4 + r;
        int byte_off = ((q * 128) + ((kt * 16 + lr) << 1)) ^ ((q & 7) << 4);
        *(short*)((char*)Pw + byte_off) = f2bf(p);
      }
    }
    // cross-lane LDS RAW within the wave: drain DS queue before reading P
    asm volatile("s_waitcnt lgkmcnt(0)" ::: "memory");

    // ---- PV: acc[q][d] += P[q][k] * V[k][d] ----
    #pragma unroll
    for (int ks = 0; ks < 2; ++ks) {
      int byteA = (lr * 128 + ((ks * 32 + lg * 8) << 1)) ^ ((lr & 7) << 4);
      bf16x8 pf = *(const bf16x8*)((char*)Pw + byteA);
      #pragma unroll
      for (int nt = 0; nt < 8; ++nt) {
        int row = nt * 16 + lr;
        int byteB = (row * 128 + ((ks * 32 + lg * 8) << 1)) ^ ((row & 7) << 4);
        bf16x8 vf = *(const bf16x8*)((char*)Vlds + byteB);
        acc[nt] = __builtin_amdgcn_mfma_f32_16x16x32_bf16(pf, vf, acc[nt], 0, 0, 0);
      }
    }
  }

  // ---- epilogue: row-sum reduce over the 16 lanes of each row group, normalize, store ----
  #pragma unroll
  for (int r = 0; r < 4; ++r) {
    float v = lsum[r];
    v += __shfl_xor(v, 1);
    v += __shfl_xor(v, 2);
    v += __shfl_xor(v, 4);
    v += __shfl_xor(v, 8);
    float inv = 1.0f / v;
    float* dst = Ob + (size_t)(qbase + w * 16 + lg * 4 + r) * DIM + lr;
    #pragma unroll
    for (int nt = 0; nt < 8; ++nt)
      dst[nt * 16] = acc[nt][r] * inv;
  }
}

extern "C" void kernel_launch(void* const* d_in, const int* in_sizes, int n_in,
                              void* d_out, int out_size, void* d_ws, size_t ws_size,
                              hipStream_t stream) {
  (void)n_in; (void)out_size; (void)d_ws; (void)ws_size;
  const float* Q = (const float*)d_in[0];
  const float* K = (const float*)d_in[1];
  const float* V = (const float*)d_in[2];
  const float* T = (const float*)d_in[3];
  float* O = (float*)d_out;
  const int B = in_sizes[0] / (SEQ * DIM);
  dim3 grid(SEQ / 64, B);
  trust_attn_kernel<<<grid, 256, 0, stream>>>(Q, K, V, T, O);
}

// Round 2
// 180.208 us; speedup vs baseline: 1.0410x; 1.0410x over previous
//
#include <hip/hip_runtime.h>

#define SEQ 2048
#define DIM 128
#define KVB 64

typedef __attribute__((ext_vector_type(8))) short bf16x8;
typedef __attribute__((ext_vector_type(4))) short short4v;
typedef __attribute__((ext_vector_type(4))) float f32x4;

__device__ __forceinline__ short f2bf(float f) {
  union { float f; unsigned u; } v; v.f = f;
  unsigned r = v.u + 0x7FFFu + ((v.u >> 16) & 1u);  // RNE
  return (short)(r >> 16);
}

// Trust-weighted attention: context = sum_k t_k*exp((q.k/sqrt(D))*t_k) * v_k / sum_k (same weights)
// One block = 64 Q rows (4 waves x 16). KV streamed in 64-row LDS tiles.
__global__ __launch_bounds__(256, 2)
void trust_attn_kernel(const float* __restrict__ Qg, const float* __restrict__ Kg,
                       const float* __restrict__ Vg, const float* __restrict__ Tg,
                       float* __restrict__ Og) {
  __shared__ short Klds[KVB * DIM];      // [64][128] bf16 rows, XOR-swizzled (^((row&7)<<4) on byte addr)
  __shared__ short Vlds[DIM * KVB];      // V^T: [128][64] bf16 rows, XOR-swizzled
  __shared__ short Plds[4][16 * KVB];    // per-wave P tile [16][64] bf16, XOR-swizzled
  __shared__ float Tlds[KVB];

  const int b = blockIdx.y;
  const int qbase = blockIdx.x * 64;
  const int tid = (int)threadIdx.x;
  const int w = tid >> 6;
  const int l = tid & 63;
  const int lr = l & 15;    // A-row / B-col / D-col index
  const int lg = l >> 4;    // k-group

  const float* Qb = Qg + (size_t)b * SEQ * DIM;
  const float* Kb = Kg + (size_t)b * SEQ * DIM;
  const float* Vb = Vg + (size_t)b * SEQ * DIM;
  const float* Tb = Tg + (size_t)b * SEQ;
  float*       Ob = Og + (size_t)b * SEQ * DIM;

  // Q fragments (A-operand, M=16 rows of this wave): row=lr, k-slot j -> d = kk*32 + lg*8 + j
  bf16x8 qf[4];
  {
    const float* qrow = Qb + (size_t)(qbase + w * 16 + lr) * DIM;
    #pragma unroll
    for (int kk = 0; kk < 4; ++kk) {
      const float4 a = *(const float4*)(qrow + kk * 32 + lg * 8);
      const float4 c = *(const float4*)(qrow + kk * 32 + lg * 8 + 4);
      bf16x8 f;
      f[0] = f2bf(a.x); f[1] = f2bf(a.y); f[2] = f2bf(a.z); f[3] = f2bf(a.w);
      f[4] = f2bf(c.x); f[5] = f2bf(c.y); f[6] = f2bf(c.z); f[7] = f2bf(c.w);
      qf[kk] = f;
    }
  }

  f32x4 acc[8];
  #pragma unroll
  for (int nt = 0; nt < 8; ++nt) acc[nt] = f32x4{0.f, 0.f, 0.f, 0.f};
  float lsum[4] = {0.f, 0.f, 0.f, 0.f};

  for (int kv0 = 0; kv0 < SEQ; kv0 += KVB) {
    __syncthreads();  // previous tile's LDS reads done before overwrite

    // ---- stage K tile [64][128] fp32 -> bf16, swizzled, vectorized ----
    #pragma unroll
    for (int i = 0; i < 8; ++i) {
      int flat4 = i * 256 + tid;          // float4-granular index, 0..2047
      int r = flat4 >> 5;                 // key row 0..63
      int c4 = (flat4 & 31) << 2;         // d col, multiple of 4
      const float4 f = *(const float4*)(Kb + (size_t)(kv0 + r) * DIM + c4);
      short4v pk;
      pk[0] = f2bf(f.x); pk[1] = f2bf(f.y); pk[2] = f2bf(f.z); pk[3] = f2bf(f.w);
      int byte_off = (r * 256 + (c4 << 1)) ^ ((r & 7) << 4);
      *(short4v*)((char*)Klds + byte_off) = pk;
    }
    // ---- stage V^T tile [128][64]: transpose at global read.
    // Each task owns Vt row d, kv-chunk of 8: reads 8 kv-strided dwords
    // (lane-consecutive d -> coalesced 256B segments), writes ONE swizzled b128.
    #pragma unroll
    for (int i = 0; i < 4; ++i) {
      int task = i * 256 + tid;           // 0..1023 = 128 d-rows x 8 kv-chunks
      int d = task & 127;
      int chunk = task >> 7;              // 0..7, kv = chunk*8 .. +7
      const float* src = Vb + (size_t)(kv0 + chunk * 8) * DIM + d;
      bf16x8 pk;
      #pragma unroll
      for (int j = 0; j < 8; ++j) pk[j] = f2bf(src[(size_t)j * DIM]);
      int byte_off = (d * 128 + chunk * 16) ^ ((d & 7) << 4);
      *(bf16x8*)((char*)Vlds + byte_off) = pk;
    }
    if (tid < KVB) Tlds[tid] = Tb[kv0 + tid];
    __syncthreads();

    // ---- QK^T: S[q=4*lg+r][key=16*kt+lr] (D-layout per m89) ----
    f32x4 s[4];
    #pragma unroll
    for (int kt = 0; kt < 4; ++kt) {
      f32x4 a0 = f32x4{0.f, 0.f, 0.f, 0.f};
      #pragma unroll
      for (int kk = 0; kk < 4; ++kk) {
        int row = kt * 16 + lr;
        int byte_off = (row * 256 + ((kk * 32 + lg * 8) << 1)) ^ ((row & 7) << 4);
        bf16x8 kf = *(const bf16x8*)((char*)Klds + byte_off);
        a0 = __builtin_amdgcn_mfma_f32_16x16x32_bf16(qf[kk], kf, a0, 0, 0, 0);
      }
      s[kt] = a0;
    }

    // ---- weights: p = t * exp2(score * t * log2(e)/sqrt(D)); no max needed (|score|<~12) ----
    short* Pw = Plds[w];
    #pragma unroll
    for (int kt = 0; kt < 4; ++kt) {
      float t = Tlds[kt * 16 + lr];
      float tc = t * 0.12751743f;  // log2(e)/sqrt(128)
      #pragma unroll
      for (int r = 0; r < 4; ++r) {
        float p = t * exp2f(s[kt][r] * tc);
        lsum[r] += p;
        int q = lg * 4 + r;
        int byte_off = ((q * 128) + ((kt * 16 + lr) << 1)) ^ ((q & 7) << 4);
        *(short*)((char*)Pw + byte_off) = f2bf(p);
      }
    }
    // cross-lane LDS RAW within the wave: drain DS queue before reading P
    asm volatile("s_waitcnt lgkmcnt(0)" ::: "memory");

    // ---- PV: acc[q][d] += P[q][k] * V[k][d] ----
    #pragma unroll
    for (int ks = 0; ks < 2; ++ks) {
      int byteA = (lr * 128 + ((ks * 32 + lg * 8) << 1)) ^ ((lr & 7) << 4);
      bf16x8 pf = *(const bf16x8*)((char*)Pw + byteA);
      #pragma unroll
      for (int nt = 0; nt < 8; ++nt) {
        int row = nt * 16 + lr;
        int byteB = (row * 128 + ((ks * 32 + lg * 8) << 1)) ^ ((row & 7) << 4);
        bf16x8 vf = *(const bf16x8*)((char*)Vlds + byteB);
        acc[nt] = __builtin_amdgcn_mfma_f32_16x16x32_bf16(pf, vf, acc[nt], 0, 0, 0);
      }
    }
  }

  // ---- epilogue: row-sum reduce over the 16 lanes of each row group, normalize, store ----
  #pragma unroll
  for (int r = 0; r < 4; ++r) {
    float v = lsum[r];
    v += __shfl_xor(v, 1);
    v += __shfl_xor(v, 2);
    v += __shfl_xor(v, 4);
    v += __shfl_xor(v, 8);
    float inv = 1.0f / v;
    float* dst = Ob + (size_t)(qbase + w * 16 + lg * 4 + r) * DIM + lr;
    #pragma unroll
    for (int nt = 0; nt < 8; ++nt)
      dst[nt * 16] = acc[nt][r] * inv;
  }
}

extern "C" void kernel_launch(void* const* d_in, const int* in_sizes, int n_in,
                              void* d_out, int out_size, void* d_ws, size_t ws_size,
                              hipStream_t stream) {
  (void)n_in; (void)out_size; (void)d_ws; (void)ws_size;
  const float* Q = (const float*)d_in[0];
  const float* K = (const float*)d_in[1];
  const float* V = (const float*)d_in[2];
  const float* T = (const float*)d_in[3];
  float* O = (float*)d_out;
  const int B = in_sizes[0] / (SEQ * DIM);
  dim3 grid(SEQ / 64, B);
  trust_attn_kernel<<<grid, 256, 0, stream>>>(Q, K, V, T, O);
}

// Round 3
// 103.298 us; speedup vs baseline: 1.8160x; 1.7446x over previous
//
#include <hip/hip_runtime.h>

#define SEQ 2048
#define DIM 128
#define KVB 64
#define NT  (SEQ / KVB)

typedef __attribute__((ext_vector_type(8))) short bf16x8;
typedef __attribute__((ext_vector_type(4))) short short4v;
typedef __attribute__((ext_vector_type(4))) float f32x4;

__device__ __forceinline__ short f2bf(float f) {
  union { float f; unsigned u; } v; v.f = f;
  unsigned r = v.u + 0x7FFFu + ((v.u >> 16) & 1u);  // RNE
  return (short)(r >> 16);
}

// Trust-weighted attention: context = sum_k t_k*exp((q.k/sqrt(D))*t_k) * v_k / sum_k (same)
// One block = 64 Q rows (4 waves x 16). KV streamed in 64-row LDS tiles,
// double-buffered, with register prefetch of tile t+1 overlapping compute of tile t.
__global__ __launch_bounds__(256, 2)
void trust_attn_kernel(const float* __restrict__ Qg, const float* __restrict__ Kg,
                       const float* __restrict__ Vg, const float* __restrict__ Tg,
                       float* __restrict__ Og) {
  __shared__ short Klds[2][KVB * DIM];   // [64][128] bf16 rows, XOR-swizzled ^((row&7)<<4)
  __shared__ short Vlds[2][DIM * KVB];   // V^T: [128][64] bf16 rows, XOR-swizzled
  __shared__ short Plds[4][16 * KVB];    // per-wave P tile [16][64] bf16, XOR-swizzled
  __shared__ float Tlds[2][KVB];

  const int b = blockIdx.y;
  const int qbase = blockIdx.x * 64;
  const int tid = (int)threadIdx.x;
  const int w = tid >> 6;
  const int l = tid & 63;
  const int lr = l & 15;    // A-row / B-col / D-col index
  const int lg = l >> 4;    // k-group

  const float* Qb = Qg + (size_t)b * SEQ * DIM;
  const float* Kb = Kg + (size_t)b * SEQ * DIM;
  const float* Vb = Vg + (size_t)b * SEQ * DIM;
  const float* Tb = Tg + (size_t)b * SEQ;
  float*       Ob = Og + (size_t)b * SEQ * DIM;

  // ---- staged registers for tile prefetch ----
  float4 kreg[8];
  float  vreg[32];
  float  treg;

  // addressing for the staging tasks (constant per thread)
  const int kr  = tid >> 5;            // base K row for i=0 (advances by 8 per i)
  const int kc4 = (tid & 31) << 2;     // K d-col (multiple of 4)
  const int vd  = tid & 127;           // V^T row d for i even (d for i*256+tid)
  // note: tasks below recompute exact indices per i to keep them compile-time static

  auto ISSUE = [&](int kv0) {
    #pragma unroll
    for (int i = 0; i < 8; ++i) {
      int flat4 = i * 256 + tid;
      int r = flat4 >> 5;
      int c4 = (flat4 & 31) << 2;
      kreg[i] = *(const float4*)(Kb + (size_t)(kv0 + r) * DIM + c4);
    }
    #pragma unroll
    for (int i = 0; i < 4; ++i) {
      int task = i * 256 + tid;
      int d = task & 127;
      int chunk = task >> 7;
      const float* src = Vb + (size_t)(kv0 + chunk * 8) * DIM + d;
      #pragma unroll
      for (int j = 0; j < 8; ++j) vreg[i * 8 + j] = src[(size_t)j * DIM];
    }
    treg = (tid < KVB) ? Tb[kv0 + tid] : 0.f;
  };

  auto STORE = [&](int buf) {
    #pragma unroll
    for (int i = 0; i < 8; ++i) {
      int flat4 = i * 256 + tid;
      int r = flat4 >> 5;
      int c4 = (flat4 & 31) << 2;
      short4v pk;
      pk[0] = f2bf(kreg[i].x); pk[1] = f2bf(kreg[i].y);
      pk[2] = f2bf(kreg[i].z); pk[3] = f2bf(kreg[i].w);
      int byte_off = (r * 256 + (c4 << 1)) ^ ((r & 7) << 4);
      *(short4v*)((char*)&Klds[buf][0] + byte_off) = pk;
    }
    #pragma unroll
    for (int i = 0; i < 4; ++i) {
      int task = i * 256 + tid;
      int d = task & 127;
      int chunk = task >> 7;
      bf16x8 pk;
      #pragma unroll
      for (int j = 0; j < 8; ++j) pk[j] = f2bf(vreg[i * 8 + j]);
      int byte_off = (d * 128 + chunk * 16) ^ ((d & 7) << 4);
      *(bf16x8*)((char*)&Vlds[buf][0] + byte_off) = pk;
    }
    if (tid < KVB) Tlds[buf][tid] = treg;
  };

  // ---- Q fragments (A-operand): row=lr, k-slot j -> d = kk*32 + lg*8 + j ----
  bf16x8 qf[4];
  {
    const float* qrow = Qb + (size_t)(qbase + w * 16 + lr) * DIM;
    #pragma unroll
    for (int kk = 0; kk < 4; ++kk) {
      const float4 a = *(const float4*)(qrow + kk * 32 + lg * 8);
      const float4 c = *(const float4*)(qrow + kk * 32 + lg * 8 + 4);
      bf16x8 f;
      f[0] = f2bf(a.x); f[1] = f2bf(a.y); f[2] = f2bf(a.z); f[3] = f2bf(a.w);
      f[4] = f2bf(c.x); f[5] = f2bf(c.y); f[6] = f2bf(c.z); f[7] = f2bf(c.w);
      qf[kk] = f;
    }
  }

  f32x4 acc[8];
  #pragma unroll
  for (int nt = 0; nt < 8; ++nt) acc[nt] = f32x4{0.f, 0.f, 0.f, 0.f};
  float lsum[4] = {0.f, 0.f, 0.f, 0.f};

  // prologue: stage tile 0
  ISSUE(0);
  STORE(0);
  __syncthreads();

  for (int t = 0; t < NT; ++t) {
    const int cur = t & 1;

    // issue next tile's global loads (latency hides under compute below)
    if (t + 1 < NT) ISSUE((t + 1) * KVB);

    const short* Kc = &Klds[cur][0];
    const short* Vc = &Vlds[cur][0];

    // ---- QK^T: S[q=4*lg+r][key=16*kt+lr] ----
    f32x4 s[4];
    #pragma unroll
    for (int kt = 0; kt < 4; ++kt) {
      f32x4 a0 = f32x4{0.f, 0.f, 0.f, 0.f};
      #pragma unroll
      for (int kk = 0; kk < 4; ++kk) {
        int row = kt * 16 + lr;
        int byte_off = (row * 256 + ((kk * 32 + lg * 8) << 1)) ^ ((row & 7) << 4);
        bf16x8 kf = *(const bf16x8*)((const char*)Kc + byte_off);
        a0 = __builtin_amdgcn_mfma_f32_16x16x32_bf16(qf[kk], kf, a0, 0, 0, 0);
      }
      s[kt] = a0;
    }

    // ---- weights: p = t * exp2(score * t * log2(e)/sqrt(D)); no max needed (|score|<~12) ----
    short* Pw = Plds[w];
    #pragma unroll
    for (int kt = 0; kt < 4; ++kt) {
      float tt = Tlds[cur][kt * 16 + lr];
      float tc = tt * 0.12751743f;  // log2(e)/sqrt(128)
      #pragma unroll
      for (int r = 0; r < 4; ++r) {
        float p = tt * exp2f(s[kt][r] * tc);
        lsum[r] += p;
        int q = lg * 4 + r;
        int byte_off = ((q * 128) + ((kt * 16 + lr) << 1)) ^ ((q & 7) << 4);
        *(short*)((char*)Pw + byte_off) = f2bf(p);
      }
    }
    // cross-lane LDS RAW within the wave: drain DS queue before reading P
    asm volatile("s_waitcnt lgkmcnt(0)" ::: "memory");

    // ---- PV: acc[q][d] += P[q][k] * V[k][d] ----
    #pragma unroll
    for (int ks = 0; ks < 2; ++ks) {
      int byteA = (lr * 128 + ((ks * 32 + lg * 8) << 1)) ^ ((lr & 7) << 4);
      bf16x8 pf = *(const bf16x8*)((char*)Pw + byteA);
      #pragma unroll
      for (int nt = 0; nt < 8; ++nt) {
        int row = nt * 16 + lr;
        int byteB = (row * 128 + ((ks * 32 + lg * 8) << 1)) ^ ((row & 7) << 4);
        bf16x8 vf = *(const bf16x8*)((const char*)Vc + byteB);
        acc[nt] = __builtin_amdgcn_mfma_f32_16x16x32_bf16(pf, vf, acc[nt], 0, 0, 0);
      }
    }

    // late half of the staging: convert + LDS write into the other buffer.
    // buf^1 was last read in iter t-1; the barrier at end of t-1 makes this safe.
    if (t + 1 < NT) {
      STORE(cur ^ 1);
      __syncthreads();
    }
  }

  // ---- epilogue: row-sum reduce over 16 lanes per row group, normalize, store ----
  #pragma unroll
  for (int r = 0; r < 4; ++r) {
    float v = lsum[r];
    v += __shfl_xor(v, 1);
    v += __shfl_xor(v, 2);
    v += __shfl_xor(v, 4);
    v += __shfl_xor(v, 8);
    float inv = 1.0f / v;
    float* dst = Ob + (size_t)(qbase + w * 16 + lg * 4 + r) * DIM + lr;
    #pragma unroll
    for (int nt = 0; nt < 8; ++nt)
      dst[nt * 16] = acc[nt][r] * inv;
  }
}

extern "C" void kernel_launch(void* const* d_in, const int* in_sizes, int n_in,
                              void* d_out, int out_size, void* d_ws, size_t ws_size,
                              hipStream_t stream) {
  (void)n_in; (void)out_size; (void)d_ws; (void)ws_size;
  const float* Q = (const float*)d_in[0];
  const float* K = (const float*)d_in[1];
  const float* V = (const float*)d_in[2];
  const float* T = (const float*)d_in[3];
  float* O = (float*)d_out;
  const int B = in_sizes[0] / (SEQ * DIM);
  dim3 grid(SEQ / 64, B);
  trust_attn_kernel<<<grid, 256, 0, stream>>>(Q, K, V, T, O);
}

// Round 4
// 84.794 us; speedup vs baseline: 2.2123x; 1.2182x over previous
//
#include <hip/hip_runtime.h>

#define SEQ 2048
#define DIM 128
#define KVB 64
#define NT  (SEQ / KVB)
#define TILE_BYTES (KVB * DIM * 2)   // 16 KB bf16 tile

typedef __attribute__((ext_vector_type(8))) short bf16x8;
typedef __attribute__((ext_vector_type(4))) short short4v;
typedef __attribute__((ext_vector_type(4))) float f32x4;

__device__ __forceinline__ short f2bf(float f) {
  union { float f; unsigned u; } v; v.f = f;
  unsigned r = v.u + 0x7FFFu + ((v.u >> 16) & 1u);  // RNE
  return (short)(r >> 16);
}

__device__ __forceinline__ void dma16(const void* g, void* l) {
  __builtin_amdgcn_global_load_lds(
      (const __attribute__((address_space(1))) void*)g,
      (__attribute__((address_space(3))) void*)l, 16, 0, 0);
}

// ================= pre-pass: K -> bf16 swizzled tiles, V -> V^T bf16 swizzled tiles =================
// ws layout: Kws[b][tile][16KB] then Vws[b][tile][16KB]; byte positions are the exact
// swizzled LDS byte offsets the main kernel reads, so the DMA is a linear copy.
__global__ __launch_bounds__(256)
void prepack_kernel(const float* __restrict__ Kg, const float* __restrict__ Vg,
                    char* __restrict__ Kws, char* __restrict__ Vws) {
  const int tile = blockIdx.x, b = blockIdx.y;
  const int tid = (int)threadIdx.x;
  const float* Kb = Kg + ((size_t)b * SEQ + tile * KVB) * DIM;
  const float* Vb = Vg + ((size_t)b * SEQ + tile * KVB) * DIM;
  char* kd = Kws + (size_t)(b * NT + tile) * TILE_BYTES;
  char* vd = Vws + (size_t)(b * NT + tile) * TILE_BYTES;

  #pragma unroll
  for (int i = 0; i < 8; ++i) {
    int flat4 = i * 256 + tid;
    int r = flat4 >> 5, c4 = (flat4 & 31) << 2;
    const float4 f = *(const float4*)(Kb + (size_t)r * DIM + c4);
    short4v pk;
    pk[0] = f2bf(f.x); pk[1] = f2bf(f.y); pk[2] = f2bf(f.z); pk[3] = f2bf(f.w);
    *(short4v*)(kd + ((r * 256 + (c4 << 1)) ^ ((r & 7) << 4))) = pk;
  }
  #pragma unroll
  for (int i = 0; i < 4; ++i) {
    int task = i * 256 + tid;
    int d = task & 127, chunk = task >> 7;
    const float* src = Vb + (size_t)(chunk * 8) * DIM + d;
    bf16x8 pk;
    #pragma unroll
    for (int j = 0; j < 8; ++j) pk[j] = f2bf(src[(size_t)j * DIM]);
    *(bf16x8*)(vd + ((d * 128 + chunk * 16) ^ ((d & 7) << 4))) = pk;
  }
}

// ================= main attention kernel: DMA-staged bf16 tiles =================
__global__ __launch_bounds__(256, 2)
void trust_attn_main(const float* __restrict__ Qg, const char* __restrict__ Kws,
                     const char* __restrict__ Vws, const float* __restrict__ Tg,
                     float* __restrict__ Og) {
  __shared__ char Klds[2][TILE_BYTES];
  __shared__ char Vlds[2][TILE_BYTES];
  __shared__ short Plds[4][16 * KVB];
  __shared__ float Tall[SEQ];

  const int b = blockIdx.y;
  const int qbase = blockIdx.x * 64;
  const int tid = (int)threadIdx.x;
  const int w = tid >> 6;
  const int l = tid & 63;
  const int lr = l & 15;
  const int lg = l >> 4;

  const float* Qb = Qg + (size_t)b * SEQ * DIM;
  float*       Ob = Og + (size_t)b * SEQ * DIM;
  const char*  Kt = Kws + (size_t)b * NT * TILE_BYTES;
  const char*  Vt = Vws + (size_t)b * NT * TILE_BYTES;

  // stage all trust scores for this batch (fp32, 8KB)
  #pragma unroll
  for (int i = 0; i < 2; ++i) {
    int f4 = i * 256 + tid;
    *(float4*)&Tall[f4 * 4] = *(const float4*)(Tg + (size_t)b * SEQ + f4 * 4);
  }

  // Q fragments: row=lr, k-slot j -> d = kk*32 + lg*8 + j
  bf16x8 qf[4];
  {
    const float* qrow = Qb + (size_t)(qbase + w * 16 + lr) * DIM;
    #pragma unroll
    for (int kk = 0; kk < 4; ++kk) {
      const float4 a = *(const float4*)(qrow + kk * 32 + lg * 8);
      const float4 c = *(const float4*)(qrow + kk * 32 + lg * 8 + 4);
      bf16x8 f;
      f[0] = f2bf(a.x); f[1] = f2bf(a.y); f[2] = f2bf(a.z); f[3] = f2bf(a.w);
      f[4] = f2bf(c.x); f[5] = f2bf(c.y); f[6] = f2bf(c.z); f[7] = f2bf(c.w);
      qf[kk] = f;
    }
  }

  f32x4 acc[8];
  #pragma unroll
  for (int nt = 0; nt < 8; ++nt) acc[nt] = f32x4{0.f, 0.f, 0.f, 0.f};
  float lsum[4] = {0.f, 0.f, 0.f, 0.f};

  // per-wave DMA: wave w copies bytes [w*4096, w*4096+4096) of each 16KB tile
  auto ISSUE = [&](int t, int buf) {
    const char* ks = Kt + (size_t)t * TILE_BYTES + w * 4096 + l * 16;
    const char* vs = Vt + (size_t)t * TILE_BYTES + w * 4096 + l * 16;
    char* kl = &Klds[buf][w * 4096];
    char* vl = &Vlds[buf][w * 4096];
    #pragma unroll
    for (int i = 0; i < 4; ++i) {
      dma16(ks + i * 1024, kl + i * 1024);
      dma16(vs + i * 1024, vl + i * 1024);
    }
  };

  ISSUE(0, 0);
  __syncthreads();  // compiler drains vmcnt before s_barrier -> tile0 resident

  for (int t = 0; t < NT; ++t) {
    const int cur = t & 1;
    if (t + 1 < NT) ISSUE(t + 1, cur ^ 1);  // flies under this tile's compute

    const char* Kc = &Klds[cur][0];
    const char* Vc = &Vlds[cur][0];

    // ---- QK^T: S[q=4*lg+r][key=16*kt+lr] ----
    f32x4 s[4];
    #pragma unroll
    for (int kt = 0; kt < 4; ++kt) {
      f32x4 a0 = f32x4{0.f, 0.f, 0.f, 0.f};
      #pragma unroll
      for (int kk = 0; kk < 4; ++kk) {
        int row = kt * 16 + lr;
        int byte_off = (row * 256 + ((kk * 32 + lg * 8) << 1)) ^ ((row & 7) << 4);
        bf16x8 kf = *(const bf16x8*)(Kc + byte_off);
        a0 = __builtin_amdgcn_mfma_f32_16x16x32_bf16(qf[kk], kf, a0, 0, 0, 0);
      }
      s[kt] = a0;
    }

    // ---- p = t * exp2(score * t * log2e/sqrt(D)); no max tracking needed (|score|<~12) ----
    short* Pw = Plds[w];
    #pragma unroll
    for (int kt = 0; kt < 4; ++kt) {
      float tt = Tall[t * KVB + kt * 16 + lr];
      float tc = tt * 0.12751743f;  // log2(e)/sqrt(128)
      #pragma unroll
      for (int r = 0; r < 4; ++r) {
        float p = tt * exp2f(s[kt][r] * tc);
        lsum[r] += p;
        int q = lg * 4 + r;
        int byte_off = ((q * 128) + ((kt * 16 + lr) << 1)) ^ ((q & 7) << 4);
        *(short*)((char*)Pw + byte_off) = f2bf(p);
      }
    }
    asm volatile("s_waitcnt lgkmcnt(0)" ::: "memory");  // cross-lane P RAW within wave

    // ---- PV: acc[q][d] += P[q][k] * V[k][d] ----
    #pragma unroll
    for (int ks = 0; ks < 2; ++ks) {
      int byteA = (lr * 128 + ((ks * 32 + lg * 8) << 1)) ^ ((lr & 7) << 4);
      bf16x8 pf = *(const bf16x8*)((char*)Pw + byteA);
      #pragma unroll
      for (int nt = 0; nt < 8; ++nt) {
        int row = nt * 16 + lr;
        int byteB = (row * 128 + ((ks * 32 + lg * 8) << 1)) ^ ((row & 7) << 4);
        bf16x8 vf = *(const bf16x8*)(Vc + byteB);
        acc[nt] = __builtin_amdgcn_mfma_f32_16x16x32_bf16(pf, vf, acc[nt], 0, 0, 0);
      }
    }

    __syncthreads();  // drains next tile's DMA + protects buffer swap
  }

  #pragma unroll
  for (int r = 0; r < 4; ++r) {
    float v = lsum[r];
    v += __shfl_xor(v, 1);
    v += __shfl_xor(v, 2);
    v += __shfl_xor(v, 4);
    v += __shfl_xor(v, 8);
    float inv = 1.0f / v;
    float* dst = Ob + (size_t)(qbase + w * 16 + lg * 4 + r) * DIM + lr;
    #pragma unroll
    for (int nt = 0; nt < 8; ++nt)
      dst[nt * 16] = acc[nt][r] * inv;
  }
}

// ================= fallback (validated R3 monolithic) for small ws =================
__global__ __launch_bounds__(256, 2)
void trust_attn_fallback(const float* __restrict__ Qg, const float* __restrict__ Kg,
                         const float* __restrict__ Vg, const float* __restrict__ Tg,
                         float* __restrict__ Og) {
  __shared__ short Klds[2][KVB * DIM];
  __shared__ short Vlds[2][DIM * KVB];
  __shared__ short Plds[4][16 * KVB];
  __shared__ float Tlds[2][KVB];

  const int b = blockIdx.y;
  const int qbase = blockIdx.x * 64;
  const int tid = (int)threadIdx.x;
  const int w = tid >> 6;
  const int l = tid & 63;
  const int lr = l & 15;
  const int lg = l >> 4;

  const float* Qb = Qg + (size_t)b * SEQ * DIM;
  const float* Kb = Kg + (size_t)b * SEQ * DIM;
  const float* Vb = Vg + (size_t)b * SEQ * DIM;
  const float* Tb = Tg + (size_t)b * SEQ;
  float*       Ob = Og + (size_t)b * SEQ * DIM;

  float4 kreg[8];
  float  vreg[32];
  float  treg;

  auto ISSUE = [&](int kv0) {
    #pragma unroll
    for (int i = 0; i < 8; ++i) {
      int flat4 = i * 256 + tid;
      int r = flat4 >> 5;
      int c4 = (flat4 & 31) << 2;
      kreg[i] = *(const float4*)(Kb + (size_t)(kv0 + r) * DIM + c4);
    }
    #pragma unroll
    for (int i = 0; i < 4; ++i) {
      int task = i * 256 + tid;
      int d = task & 127;
      int chunk = task >> 7;
      const float* src = Vb + (size_t)(kv0 + chunk * 8) * DIM + d;
      #pragma unroll
      for (int j = 0; j < 8; ++j) vreg[i * 8 + j] = src[(size_t)j * DIM];
    }
    treg = (tid < KVB) ? Tb[kv0 + tid] : 0.f;
  };

  auto STORE = [&](int buf) {
    #pragma unroll
    for (int i = 0; i < 8; ++i) {
      int flat4 = i * 256 + tid;
      int r = flat4 >> 5;
      int c4 = (flat4 & 31) << 2;
      short4v pk;
      pk[0] = f2bf(kreg[i].x); pk[1] = f2bf(kreg[i].y);
      pk[2] = f2bf(kreg[i].z); pk[3] = f2bf(kreg[i].w);
      int byte_off = (r * 256 + (c4 << 1)) ^ ((r & 7) << 4);
      *(short4v*)((char*)&Klds[buf][0] + byte_off) = pk;
    }
    #pragma unroll
    for (int i = 0; i < 4; ++i) {
      int task = i * 256 + tid;
      int d = task & 127;
      int chunk = task >> 7;
      bf16x8 pk;
      #pragma unroll
      for (int j = 0; j < 8; ++j) pk[j] = f2bf(vreg[i * 8 + j]);
      int byte_off = (d * 128 + chunk * 16) ^ ((d & 7) << 4);
      *(bf16x8*)((char*)&Vlds[buf][0] + byte_off) = pk;
    }
    if (tid < KVB) Tlds[buf][tid] = treg;
  };

  bf16x8 qf[4];
  {
    const float* qrow = Qb + (size_t)(qbase + w * 16 + lr) * DIM;
    #pragma unroll
    for (int kk = 0; kk < 4; ++kk) {
      const float4 a = *(const float4*)(qrow + kk * 32 + lg * 8);
      const float4 c = *(const float4*)(qrow + kk * 32 + lg * 8 + 4);
      bf16x8 f;
      f[0] = f2bf(a.x); f[1] = f2bf(a.y); f[2] = f2bf(a.z); f[3] = f2bf(a.w);
      f[4] = f2bf(c.x); f[5] = f2bf(c.y); f[6] = f2bf(c.z); f[7] = f2bf(c.w);
      qf[kk] = f;
    }
  }

  f32x4 acc[8];
  #pragma unroll
  for (int nt = 0; nt < 8; ++nt) acc[nt] = f32x4{0.f, 0.f, 0.f, 0.f};
  float lsum[4] = {0.f, 0.f, 0.f, 0.f};

  ISSUE(0);
  STORE(0);
  __syncthreads();

  for (int t = 0; t < NT; ++t) {
    const int cur = t & 1;
    if (t + 1 < NT) ISSUE((t + 1) * KVB);

    const short* Kc = &Klds[cur][0];
    const short* Vc = &Vlds[cur][0];

    f32x4 s[4];
    #pragma unroll
    for (int kt = 0; kt < 4; ++kt) {
      f32x4 a0 = f32x4{0.f, 0.f, 0.f, 0.f};
      #pragma unroll
      for (int kk = 0; kk < 4; ++kk) {
        int row = kt * 16 + lr;
        int byte_off = (row * 256 + ((kk * 32 + lg * 8) << 1)) ^ ((row & 7) << 4);
        bf16x8 kf = *(const bf16x8*)((const char*)Kc + byte_off);
        a0 = __builtin_amdgcn_mfma_f32_16x16x32_bf16(qf[kk], kf, a0, 0, 0, 0);
      }
      s[kt] = a0;
    }

    short* Pw = Plds[w];
    #pragma unroll
    for (int kt = 0; kt < 4; ++kt) {
      float tt = Tlds[cur][kt * 16 + lr];
      float tc = tt * 0.12751743f;
      #pragma unroll
      for (int r = 0; r < 4; ++r) {
        float p = tt * exp2f(s[kt][r] * tc);
        lsum[r] += p;
        int q = lg * 4 + r;
        int byte_off = ((q * 128) + ((kt * 16 + lr) << 1)) ^ ((q & 7) << 4);
        *(short*)((char*)Pw + byte_off) = f2bf(p);
      }
    }
    asm volatile("s_waitcnt lgkmcnt(0)" ::: "memory");

    #pragma unroll
    for (int ks = 0; ks < 2; ++ks) {
      int byteA = (lr * 128 + ((ks * 32 + lg * 8) << 1)) ^ ((lr & 7) << 4);
      bf16x8 pf = *(const bf16x8*)((char*)Pw + byteA);
      #pragma unroll
      for (int nt = 0; nt < 8; ++nt) {
        int row = nt * 16 + lr;
        int byteB = (row * 128 + ((ks * 32 + lg * 8) << 1)) ^ ((row & 7) << 4);
        bf16x8 vf = *(const bf16x8*)((const char*)Vc + byteB);
        acc[nt] = __builtin_amdgcn_mfma_f32_16x16x32_bf16(pf, vf, acc[nt], 0, 0, 0);
      }
    }

    if (t + 1 < NT) {
      STORE(cur ^ 1);
      __syncthreads();
    }
  }

  #pragma unroll
  for (int r = 0; r < 4; ++r) {
    float v = lsum[r];
    v += __shfl_xor(v, 1);
    v += __shfl_xor(v, 2);
    v += __shfl_xor(v, 4);
    v += __shfl_xor(v, 8);
    float inv = 1.0f / v;
    float* dst = Ob + (size_t)(qbase + w * 16 + lg * 4 + r) * DIM + lr;
    #pragma unroll
    for (int nt = 0; nt < 8; ++nt)
      dst[nt * 16] = acc[nt][r] * inv;
  }
}

extern "C" void kernel_launch(void* const* d_in, const int* in_sizes, int n_in,
                              void* d_out, int out_size, void* d_ws, size_t ws_size,
                              hipStream_t stream) {
  (void)n_in; (void)out_size;
  const float* Q = (const float*)d_in[0];
  const float* K = (const float*)d_in[1];
  const float* V = (const float*)d_in[2];
  const float* T = (const float*)d_in[3];
  float* O = (float*)d_out;
  const int B = in_sizes[0] / (SEQ * DIM);

  const size_t need = (size_t)B * NT * TILE_BYTES * 2;
  if (ws_size >= need) {
    char* Kws = (char*)d_ws;
    char* Vws = Kws + (size_t)B * NT * TILE_BYTES;
    dim3 grid(NT, B);
    prepack_kernel<<<grid, 256, 0, stream>>>(K, V, Kws, Vws);
    dim3 grid2(SEQ / 64, B);
    trust_attn_main<<<grid2, 256, 0, stream>>>(Q, Kws, Vws, T, O);
  } else {
    dim3 grid(SEQ / 64, B);
    trust_attn_fallback<<<grid, 256, 0, stream>>>(Q, K, V, T, O);
  }
}

// Round 5
// 71.929 us; speedup vs baseline: 2.6080x; 1.1789x over previous
//
#include <hip/hip_runtime.h>
#include <math.h>

#define SEQ 2048
#define DIM 128
#define KVB 32
#define QB  128
#define NTILES 64            // KVB-tiles per batch
#define NT2 32               // tiles per wave-group (half the keys)
#define TB  (KVB * DIM * 2)  // 8192 B per packed tile

typedef __attribute__((ext_vector_type(8))) short bf16x8;
typedef __attribute__((ext_vector_type(4))) short short4v;
typedef __attribute__((ext_vector_type(4))) float f32x4;

__device__ __forceinline__ short f2bf(float f) {
  union { float f; unsigned u; } v; v.f = f;
  unsigned r = v.u + 0x7FFFu + ((v.u >> 16) & 1u);  // RNE
  return (short)(r >> 16);
}

__device__ __forceinline__ void dma16(const void* g, void* l) {
  __builtin_amdgcn_global_load_lds(
      (const __attribute__((address_space(1))) void*)g,
      (__attribute__((address_space(3))) void*)l, 16, 0, 0);
}

// ============ pre-pass: K -> swizzled bf16 tiles; V -> V^T bf16 tiles; T -> (t*log2e/sqrtD, log2 t) ============
__global__ __launch_bounds__(256)
void prepack_kernel(const float* __restrict__ Kg, const float* __restrict__ Vg,
                    const float* __restrict__ Tg,
                    char* __restrict__ Kws, char* __restrict__ Vws,
                    float2* __restrict__ Taux) {
  const int tile = blockIdx.x, b = blockIdx.y;
  const int tid = (int)threadIdx.x;
  const float* Kb = Kg + ((size_t)b * SEQ + tile * KVB) * DIM;
  const float* Vb = Vg + ((size_t)b * SEQ + tile * KVB) * DIM;
  char* kd = Kws + (size_t)(b * NTILES + tile) * TB;
  char* vd = Vws + (size_t)(b * NTILES + tile) * TB;

  // K tile [32][128] -> bf16 rows (256 B), swizzled ^((row&7)<<4)
  #pragma unroll
  for (int i = 0; i < 4; ++i) {
    int flat4 = i * 256 + tid;            // 0..1023 float4 tasks
    int r = flat4 >> 5, c4 = (flat4 & 31) << 2;
    const float4 f = *(const float4*)(Kb + (size_t)r * DIM + c4);
    short4v pk;
    pk[0] = f2bf(f.x); pk[1] = f2bf(f.y); pk[2] = f2bf(f.z); pk[3] = f2bf(f.w);
    *(short4v*)(kd + ((r * 256 + (c4 << 1)) ^ ((r & 7) << 4))) = pk;
  }
  // V^T tile [128 d][32 k] -> bf16 rows (64 B, dense -> no swizzle needed)
  #pragma unroll
  for (int i = 0; i < 2; ++i) {
    int task = i * 256 + tid;             // 0..511 = 128 d x 4 chunks
    int d = task & 127, ch = task >> 7;
    const float* src = Vb + (size_t)(ch * 8) * DIM + d;
    bf16x8 pk;
    #pragma unroll
    for (int j = 0; j < 8; ++j) pk[j] = f2bf(src[(size_t)j * DIM]);
    *(bf16x8*)(vd + d * 64 + ch * 16) = pk;
  }
  if (tid < KVB) {
    int k = tile * KVB + tid;
    float t = Tg[(size_t)b * SEQ + k];
    Taux[(size_t)b * SEQ + k] = make_float2(t * 0.12751743f, log2f(t));  // log2e/sqrt(128)
  }
}

// ============ main: 512 thr = 2 key-groups x 4 waves; 32 q-rows/wave; in-LDS split-KV combine ============
__global__ __launch_bounds__(512, 2)
void trust_attn_main(const float* __restrict__ Qg, const char* __restrict__ Kws,
                     const char* __restrict__ Vws, const float2* __restrict__ Taux,
                     float* __restrict__ Og) {
  // carve 96 KB: K [2g][2buf][8KB] | V [2][2][8KB] | P [8 waves][2KB] | Ta [2][1024 float2]
  __shared__ __align__(16) char smem[98304];
  char*   KL = smem;
  char*   VL = smem + 32768;
  char*   PL = smem + 65536;
  float2* TA = (float2*)(smem + 81920);

  const int b = blockIdx.y;
  const int qb0 = blockIdx.x * QB;
  const int tid = (int)threadIdx.x;
  const int w = tid >> 6, g = w >> 2, wg = w & 3;
  const int l = tid & 63, lr = l & 15, lg = l >> 4;

  const float* Qb = Qg + (size_t)b * SEQ * DIM;
  float*       Ob = Og + (size_t)b * SEQ * DIM;
  const char*  Ktb = Kws + (size_t)b * NTILES * TB;
  const char*  Vtb = Vws + (size_t)b * NTILES * TB;

  // stage Taux (16 KB linear)
  {
    const float4* src = (const float4*)(Taux + (size_t)b * SEQ);
    float4* dst = (float4*)TA;
    dst[tid] = src[tid];
    dst[tid + 512] = src[tid + 512];
  }

  // Q fragments: 2 x 16-row frags; row = lr, slot j -> d = kk*32 + lg*8 + j
  const int qwave = qb0 + wg * 32;
  bf16x8 qf[2][4];
  #pragma unroll
  for (int f = 0; f < 2; ++f) {
    const float* qrow = Qb + (size_t)(qwave + f * 16 + lr) * DIM;
    #pragma unroll
    for (int kk = 0; kk < 4; ++kk) {
      const float4 a = *(const float4*)(qrow + kk * 32 + lg * 8);
      const float4 c = *(const float4*)(qrow + kk * 32 + lg * 8 + 4);
      bf16x8 q8;
      q8[0] = f2bf(a.x); q8[1] = f2bf(a.y); q8[2] = f2bf(a.z); q8[3] = f2bf(a.w);
      q8[4] = f2bf(c.x); q8[5] = f2bf(c.y); q8[6] = f2bf(c.z); q8[7] = f2bf(c.w);
      qf[f][kk] = q8;
    }
  }

  f32x4 acc[2][8];
  #pragma unroll
  for (int f = 0; f < 2; ++f)
    #pragma unroll
    for (int nt = 0; nt < 8; ++nt) acc[f][nt] = f32x4{0.f, 0.f, 0.f, 0.f};
  float lsum[2][4] = {{0.f,0.f,0.f,0.f},{0.f,0.f,0.f,0.f}};

  auto ISSUE = [&](int t, int buf) {
    const size_t toff = (size_t)(g * NT2 + t) * TB + wg * 2048 + l * 16;
    char* kl = KL + (g * 2 + buf) * 8192 + wg * 2048 + l * 16;
    char* vl = VL + (g * 2 + buf) * 8192 + wg * 2048 + l * 16;
    dma16(Ktb + toff, kl); dma16(Ktb + toff + 1024, kl + 1024);
    dma16(Vtb + toff, vl); dma16(Vtb + toff + 1024, vl + 1024);
  };

  ISSUE(0, 0);
  __syncthreads();

  for (int t = 0; t < NT2; ++t) {
    const int cur = t & 1;
    if (t + 1 < NT2) ISSUE(t + 1, cur ^ 1);
    const char* Kc = KL + (g * 2 + cur) * 8192;
    const char* Vc = VL + (g * 2 + cur) * 8192;

    // ---- QK^T: S[q=16f+4lg+r][k=16kt+lr] ----
    f32x4 s[2][2];
    #pragma unroll
    for (int f = 0; f < 2; ++f)
      #pragma unroll
      for (int kt = 0; kt < 2; ++kt) s[f][kt] = f32x4{0.f, 0.f, 0.f, 0.f};
    #pragma unroll
    for (int kt = 0; kt < 2; ++kt) {
      bf16x8 kf[4];
      #pragma unroll
      for (int kk = 0; kk < 4; ++kk)
        kf[kk] = *(const bf16x8*)(Kc + (((16 * kt + lr) * 256 + ((kk * 32 + lg * 8) << 1)) ^ ((lr & 7) << 4)));
      #pragma unroll
      for (int f = 0; f < 2; ++f)
        #pragma unroll
        for (int kk = 0; kk < 4; ++kk)
          s[f][kt] = __builtin_amdgcn_mfma_f32_16x16x32_bf16(qf[f][kk], kf[kk], s[f][kt], 0, 0, 0);
    }

    // ---- p = 2^(s*tc + lt) (= t*exp(s*t/sqrtD)); truncate->bf16, lsum on truncated value ----
    short* Pw = (short*)(PL + w * 2048);
    #pragma unroll
    for (int kt = 0; kt < 2; ++kt) {
      const float2 t2 = TA[g * 1024 + t * KVB + kt * 16 + lr];
      #pragma unroll
      for (int f = 0; f < 2; ++f)
        #pragma unroll
        for (int r = 0; r < 4; ++r) {
          float e = exp2f(fmaf(s[f][kt][r], t2.x, t2.y));
          unsigned ub = __float_as_uint(e) & 0xffff0000u;
          lsum[f][r] += __uint_as_float(ub);
          int q = f * 16 + 4 * lg + r;
          int byte_off = ((q * 64 + (kt * 16 + lr) * 2)) ^ (lg << 4);  // swz=((q>>2)&3)<<4 = lg<<4
          *(short*)((char*)Pw + byte_off) = (short)(ub >> 16);
        }
    }
    asm volatile("s_waitcnt lgkmcnt(0)" ::: "memory");  // cross-lane P RAW within wave

    // ---- PV: acc[q][d] += P[q][k] * V^T[d][k], K-dim = 32 = one MFMA pass ----
    bf16x8 pf[2];
    #pragma unroll
    for (int f = 0; f < 2; ++f)
      pf[f] = *(const bf16x8*)((char*)Pw + (((f * 16 + lr) * 64 + lg * 16) ^ (((lr >> 2) & 3) << 4)));
    #pragma unroll
    for (int nt = 0; nt < 8; ++nt) {
      bf16x8 vf = *(const bf16x8*)(Vc + (nt * 16 + lr) * 64 + lg * 16);
      #pragma unroll
      for (int f = 0; f < 2; ++f)
        acc[f][nt] = __builtin_amdgcn_mfma_f32_16x16x32_bf16(pf[f], vf, acc[f][nt], 0, 0, 0);
    }

    __syncthreads();  // drains DMA for next tile + protects dbuf swap
  }

  // ---- epilogue: reduce lsum over lr; exchange group-1 partials via LDS; combine+store by group 0 ----
  float ls[2][4];
  #pragma unroll
  for (int f = 0; f < 2; ++f)
    #pragma unroll
    for (int r = 0; r < 4; ++r) {
      float v = lsum[f][r];
      v += __shfl_xor(v, 1);
      v += __shfl_xor(v, 2);
      v += __shfl_xor(v, 4);
      v += __shfl_xor(v, 8);
      ls[f][r] = v;
    }

  __syncthreads();  // all tile/P/T LDS dead; reuse space below
  float* Accx = (float*)smem;            // [128 d][128 q] f32, swz ^((d&7)<<4)
  float* Ls   = (float*)(smem + 65536);  // [2][128]

  if (lr == 0) {
    #pragma unroll
    for (int f = 0; f < 2; ++f)
      #pragma unroll
      for (int r = 0; r < 4; ++r)
        Ls[g * 128 + wg * 32 + f * 16 + 4 * lg + r] = ls[f][r];
  }
  if (g == 1) {
    #pragma unroll
    for (int f = 0; f < 2; ++f)
      #pragma unroll
      for (int nt = 0; nt < 8; ++nt) {
        int byte_off = (((nt * 16 + lr) * 512 + (wg * 32 + f * 16 + 4 * lg) * 4)) ^ ((lr & 7) << 4);
        *(f32x4*)((char*)Accx + byte_off) = acc[f][nt];
      }
  }
  __syncthreads();
  if (g == 0) {
    #pragma unroll
    for (int f = 0; f < 2; ++f) {
      const float4 l0 = *(const float4*)&Ls[wg * 32 + f * 16 + 4 * lg];
      const float4 l1 = *(const float4*)&Ls[128 + wg * 32 + f * 16 + 4 * lg];
      float inv[4];
      inv[0] = 1.0f / (l0.x + l1.x); inv[1] = 1.0f / (l0.y + l1.y);
      inv[2] = 1.0f / (l0.z + l1.z); inv[3] = 1.0f / (l0.w + l1.w);
      #pragma unroll
      for (int nt = 0; nt < 8; ++nt) {
        int byte_off = (((nt * 16 + lr) * 512 + (wg * 32 + f * 16 + 4 * lg) * 4)) ^ ((lr & 7) << 4);
        f32x4 o = *(const f32x4*)((char*)Accx + byte_off);
        #pragma unroll
        for (int r = 0; r < 4; ++r)
          Ob[(size_t)(qwave + f * 16 + 4 * lg + r) * DIM + nt * 16 + lr] = (acc[f][nt][r] + o[r]) * inv[r];
      }
    }
  }
}

// ============ fallback (validated R3 monolithic) for small ws ============
__global__ __launch_bounds__(256, 2)
void trust_attn_fallback(const float* __restrict__ Qg, const float* __restrict__ Kg,
                         const float* __restrict__ Vg, const float* __restrict__ Tg,
                         float* __restrict__ Og) {
  __shared__ short Klds[2][64 * DIM];
  __shared__ short Vlds[2][DIM * 64];
  __shared__ short Plds[4][16 * 64];
  __shared__ float Tlds[2][64];

  const int b = blockIdx.y;
  const int qbase = blockIdx.x * 64;
  const int tid = (int)threadIdx.x;
  const int w = tid >> 6;
  const int l = tid & 63;
  const int lr = l & 15;
  const int lg = l >> 4;

  const float* Qb = Qg + (size_t)b * SEQ * DIM;
  const float* Kb = Kg + (size_t)b * SEQ * DIM;
  const float* Vb = Vg + (size_t)b * SEQ * DIM;
  const float* Tb = Tg + (size_t)b * SEQ;
  float*       Ob = Og + (size_t)b * SEQ * DIM;

  float4 kreg[8];
  float  vreg[32];
  float  treg;

  auto ISSUE = [&](int kv0) {
    #pragma unroll
    for (int i = 0; i < 8; ++i) {
      int flat4 = i * 256 + tid;
      int r = flat4 >> 5;
      int c4 = (flat4 & 31) << 2;
      kreg[i] = *(const float4*)(Kb + (size_t)(kv0 + r) * DIM + c4);
    }
    #pragma unroll
    for (int i = 0; i < 4; ++i) {
      int task = i * 256 + tid;
      int d = task & 127;
      int chunk = task >> 7;
      const float* src = Vb + (size_t)(kv0 + chunk * 8) * DIM + d;
      #pragma unroll
      for (int j = 0; j < 8; ++j) vreg[i * 8 + j] = src[(size_t)j * DIM];
    }
    treg = (tid < 64) ? Tb[kv0 + tid] : 0.f;
  };

  auto STORE = [&](int buf) {
    #pragma unroll
    for (int i = 0; i < 8; ++i) {
      int flat4 = i * 256 + tid;
      int r = flat4 >> 5;
      int c4 = (flat4 & 31) << 2;
      short4v pk;
      pk[0] = f2bf(kreg[i].x); pk[1] = f2bf(kreg[i].y);
      pk[2] = f2bf(kreg[i].z); pk[3] = f2bf(kreg[i].w);
      int byte_off = (r * 256 + (c4 << 1)) ^ ((r & 7) << 4);
      *(short4v*)((char*)&Klds[buf][0] + byte_off) = pk;
    }
    #pragma unroll
    for (int i = 0; i < 4; ++i) {
      int task = i * 256 + tid;
      int d = task & 127;
      int chunk = task >> 7;
      bf16x8 pk;
      #pragma unroll
      for (int j = 0; j < 8; ++j) pk[j] = f2bf(vreg[i * 8 + j]);
      int byte_off = (d * 128 + chunk * 16) ^ ((d & 7) << 4);
      *(bf16x8*)((char*)&Vlds[buf][0] + byte_off) = pk;
    }
    if (tid < 64) Tlds[buf][tid] = treg;
  };

  bf16x8 qf[4];
  {
    const float* qrow = Qb + (size_t)(qbase + w * 16 + lr) * DIM;
    #pragma unroll
    for (int kk = 0; kk < 4; ++kk) {
      const float4 a = *(const float4*)(qrow + kk * 32 + lg * 8);
      const float4 c = *(const float4*)(qrow + kk * 32 + lg * 8 + 4);
      bf16x8 f;
      f[0] = f2bf(a.x); f[1] = f2bf(a.y); f[2] = f2bf(a.z); f[3] = f2bf(a.w);
      f[4] = f2bf(c.x); f[5] = f2bf(c.y); f[6] = f2bf(c.z); f[7] = f2bf(c.w);
      qf[kk] = f;
    }
  }

  f32x4 acc[8];
  #pragma unroll
  for (int nt = 0; nt < 8; ++nt) acc[nt] = f32x4{0.f, 0.f, 0.f, 0.f};
  float lsum[4] = {0.f, 0.f, 0.f, 0.f};

  ISSUE(0);
  STORE(0);
  __syncthreads();

  for (int t = 0; t < SEQ / 64; ++t) {
    const int cur = t & 1;
    if (t + 1 < SEQ / 64) ISSUE((t + 1) * 64);

    const short* Kc = &Klds[cur][0];
    const short* Vc = &Vlds[cur][0];

    f32x4 s[4];
    #pragma unroll
    for (int kt = 0; kt < 4; ++kt) {
      f32x4 a0 = f32x4{0.f, 0.f, 0.f, 0.f};
      #pragma unroll
      for (int kk = 0; kk < 4; ++kk) {
        int row = kt * 16 + lr;
        int byte_off = (row * 256 + ((kk * 32 + lg * 8) << 1)) ^ ((row & 7) << 4);
        bf16x8 kf = *(const bf16x8*)((const char*)Kc + byte_off);
        a0 = __builtin_amdgcn_mfma_f32_16x16x32_bf16(qf[kk], kf, a0, 0, 0, 0);
      }
      s[kt] = a0;
    }

    short* Pw = Plds[w];
    #pragma unroll
    for (int kt = 0; kt < 4; ++kt) {
      float tt = Tlds[cur][kt * 16 + lr];
      float tc = tt * 0.12751743f;
      #pragma unroll
      for (int r = 0; r < 4; ++r) {
        float p = tt * exp2f(s[kt][r] * tc);
        lsum[r] += p;
        int q = lg * 4 + r;
        int byte_off = ((q * 128) + ((kt * 16 + lr) << 1)) ^ ((q & 7) << 4);
        *(short*)((char*)Pw + byte_off) = f2bf(p);
      }
    }
    asm volatile("s_waitcnt lgkmcnt(0)" ::: "memory");

    #pragma unroll
    for (int ks = 0; ks < 2; ++ks) {
      int byteA = (lr * 128 + ((ks * 32 + lg * 8) << 1)) ^ ((lr & 7) << 4);
      bf16x8 pf = *(const bf16x8*)((char*)Pw + byteA);
      #pragma unroll
      for (int nt = 0; nt < 8; ++nt) {
        int row = nt * 16 + lr;
        int byteB = (row * 128 + ((ks * 32 + lg * 8) << 1)) ^ ((row & 7) << 4);
        bf16x8 vf = *(const bf16x8*)((const char*)Vc + byteB);
        acc[nt] = __builtin_amdgcn_mfma_f32_16x16x32_bf16(pf, vf, acc[nt], 0, 0, 0);
      }
    }

    if (t + 1 < SEQ / 64) {
      STORE(cur ^ 1);
      __syncthreads();
    }
  }

  #pragma unroll
  for (int r = 0; r < 4; ++r) {
    float v = lsum[r];
    v += __shfl_xor(v, 1);
    v += __shfl_xor(v, 2);
    v += __shfl_xor(v, 4);
    v += __shfl_xor(v, 8);
    float inv = 1.0f / v;
    float* dst = Ob + (size_t)(qbase + w * 16 + lg * 4 + r) * DIM + lr;
    #pragma unroll
    for (int nt = 0; nt < 8; ++nt)
      dst[nt * 16] = acc[nt][r] * inv;
  }
}

extern "C" void kernel_launch(void* const* d_in, const int* in_sizes, int n_in,
                              void* d_out, int out_size, void* d_ws, size_t ws_size,
                              hipStream_t stream) {
  (void)n_in; (void)out_size;
  const float* Q = (const float*)d_in[0];
  const float* K = (const float*)d_in[1];
  const float* V = (const float*)d_in[2];
  const float* T = (const float*)d_in[3];
  float* O = (float*)d_out;
  const int B = in_sizes[0] / (SEQ * DIM);

  const size_t kv_bytes = (size_t)B * NTILES * TB;            // per tensor
  const size_t need = kv_bytes * 2 + (size_t)B * SEQ * sizeof(float2);
  if (ws_size >= need) {
    char* Kws = (char*)d_ws;
    char* Vws = Kws + kv_bytes;
    float2* Taux = (float2*)(Vws + kv_bytes);
    dim3 gridp(NTILES, B);
    prepack_kernel<<<gridp, 256, 0, stream>>>(K, V, T, Kws, Vws, Taux);
    dim3 gridm(SEQ / QB, B);
    trust_attn_main<<<gridm, 512, 0, stream>>>(Q, Kws, Vws, Taux, O);
  } else {
    dim3 grid(SEQ / 64, B);
    trust_attn_fallback<<<grid, 256, 0, stream>>>(Q, K, V, T, O);
  }
}